// Round 1
// baseline (270.073 us; speedup 1.0000x reference)
//
#include <hip/hip_runtime.h>

#define N_NODES 100000
#define N_EDGES 1600000
#define D_FEAT 64

// One wave (64 threads) per node. Lane t owns feature t.
// target_index is sorted -> binary-search the node's edge range, gather-sum.
// No atomics, no output pre-zeroing needed (empty nodes store 0).
__global__ __launch_bounds__(64) void MessagePassing_kernel(
    const float* __restrict__ x,          // [N_NODES, D_FEAT]
    const float* __restrict__ edge_values, // [N_EDGES]
    const int*   __restrict__ target_index,// [N_EDGES] sorted
    const int*   __restrict__ source_index,// [N_EDGES]
    float*       __restrict__ out)         // [N_NODES, D_FEAT]
{
    const int node = blockIdx.x;
    const int t    = threadIdx.x; // 0..63

    // lower_bound(target_index, node) — wave-uniform
    int lo = 0, hi = N_EDGES;
    while (lo < hi) {
        int mid = (lo + hi) >> 1;
        if (target_index[mid] < node) lo = mid + 1; else hi = mid;
    }
    const int start = lo;

    // lower_bound(target_index, node+1) — continue from start
    hi = N_EDGES;
    while (lo < hi) {
        int mid = (lo + hi) >> 1;
        if (target_index[mid] < node + 1) lo = mid + 1; else hi = mid;
    }
    const int end = lo;

    float acc = 0.0f;
    for (int e = start; e < end; ++e) {
        const int   s = source_index[e];   // wave-uniform broadcast
        const float w = edge_values[e];    // wave-uniform broadcast
        acc = fmaf(w, x[s * D_FEAT + t], acc); // coalesced 256B row read
    }
    out[node * D_FEAT + t] = acc;
}

extern "C" void kernel_launch(void* const* d_in, const int* in_sizes, int n_in,
                              void* d_out, int out_size, void* d_ws, size_t ws_size,
                              hipStream_t stream) {
    const float* x            = (const float*)d_in[0];
    const float* edge_values  = (const float*)d_in[1];
    const int*   target_index = (const int*)d_in[2];
    const int*   source_index = (const int*)d_in[3];
    float*       out          = (float*)d_out;

    MessagePassing_kernel<<<N_NODES, 64, 0, stream>>>(
        x, edge_values, target_index, source_index, out);
}

// Round 2
// 148.003 us; speedup vs baseline: 1.8248x; 1.8248x over previous
//
#include <hip/hip_runtime.h>

#define N_NODES 100000
#define N_EDGES 1600000
#define D_FEAT 64

// ---------------------------------------------------------------------------
// Kernel 1: build CSR row_ptr from the sorted target_index.
// row_ptr[n] = lower_bound(target_index, n); row_ptr[N_NODES] = N_EDGES.
// Edge-parallel boundary fill: thread e fills nodes (tgt[e-1], tgt[e]].
// Total scatter work = N_EDGES + N_NODES + 1.
// ---------------------------------------------------------------------------
__global__ __launch_bounds__(256) void build_row_ptr(
    const int* __restrict__ tgt, int* __restrict__ row_ptr)
{
    int e = blockIdx.x * blockDim.x + threadIdx.x;
    if (e >= N_EDGES) return;
    int cur = tgt[e];
    int lo  = (e == 0) ? 0 : tgt[e - 1] + 1;
    for (int n = lo; n <= cur; ++n) row_ptr[n] = e;
    if (e == N_EDGES - 1) {
        for (int n = cur + 1; n <= N_NODES; ++n) row_ptr[n] = N_EDGES;
    }
}

// ---------------------------------------------------------------------------
// Kernel 2: gather-sum. One wave per node; wave split into 4 edge-groups of
// 16 lanes; each lane owns a float4 of features. 4 independent edges in
// flight per loop trip; cross-group reduce via shfl_xor(16/32).
// 4 nodes (waves) per 256-thread block.
// ---------------------------------------------------------------------------
__global__ __launch_bounds__(256) void gather_sum(
    const float4* __restrict__ x4,        // [N_NODES, 16] float4
    const float*  __restrict__ ev,        // [N_EDGES]
    const int*    __restrict__ src,       // [N_EDGES]
    const int*    __restrict__ row_ptr,   // [N_NODES+1]
    float4*       __restrict__ out4)      // [N_NODES, 16] float4
{
    const int node = blockIdx.x * 4 + (threadIdx.x >> 6);
    if (node >= N_NODES) return;
    const int lane = threadIdx.x & 63;
    const int g    = lane >> 4;   // edge subgroup 0..3
    const int f    = lane & 15;   // float4 index within the row

    const int start = row_ptr[node];
    const int end   = row_ptr[node + 1];

    float4 acc = make_float4(0.f, 0.f, 0.f, 0.f);
    for (int e0 = start; e0 < end; e0 += 4) {
        const int  e     = e0 + g;
        const bool valid = (e < end);
        const int  es    = valid ? e : start;      // clamp: start is in-range here
        const float w    = valid ? ev[es] : 0.0f;  // inactive groups contribute 0
        const int   s    = src[es];
        const float4 v   = x4[s * 16 + f];         // 16 lanes x 16B contiguous per group
        acc.x = fmaf(w, v.x, acc.x);
        acc.y = fmaf(w, v.y, acc.y);
        acc.z = fmaf(w, v.z, acc.z);
        acc.w = fmaf(w, v.w, acc.w);
    }

    // reduce the 4 edge-groups: lanes xor 16 then xor 32
    acc.x += __shfl_xor(acc.x, 16, 64);
    acc.y += __shfl_xor(acc.y, 16, 64);
    acc.z += __shfl_xor(acc.z, 16, 64);
    acc.w += __shfl_xor(acc.w, 16, 64);
    acc.x += __shfl_xor(acc.x, 32, 64);
    acc.y += __shfl_xor(acc.y, 32, 64);
    acc.z += __shfl_xor(acc.z, 32, 64);
    acc.w += __shfl_xor(acc.w, 32, 64);

    if (g == 0) out4[node * 16 + f] = acc;
}

extern "C" void kernel_launch(void* const* d_in, const int* in_sizes, int n_in,
                              void* d_out, int out_size, void* d_ws, size_t ws_size,
                              hipStream_t stream) {
    const float* x            = (const float*)d_in[0];
    const float* edge_values  = (const float*)d_in[1];
    const int*   target_index = (const int*)d_in[2];
    const int*   source_index = (const int*)d_in[3];
    float*       out          = (float*)d_out;
    int*         row_ptr      = (int*)d_ws;   // (N_NODES+1) * 4 bytes

    build_row_ptr<<<(N_EDGES + 255) / 256, 256, 0, stream>>>(target_index, row_ptr);

    gather_sum<<<(N_NODES + 3) / 4, 256, 0, stream>>>(
        (const float4*)x, edge_values, source_index, row_ptr, (float4*)out);
}

// Round 3
// 141.676 us; speedup vs baseline: 1.9063x; 1.0447x over previous
//
#include <hip/hip_runtime.h>

#define N_NODES 100000
#define N_EDGES 1600000
#define D_FEAT 64

// ---------------------------------------------------------------------------
// Kernel 1: build CSR row_ptr from the sorted target_index.
// ---------------------------------------------------------------------------
__global__ __launch_bounds__(256) void build_row_ptr(
    const int* __restrict__ tgt, int* __restrict__ row_ptr)
{
    int e = blockIdx.x * blockDim.x + threadIdx.x;
    if (e >= N_EDGES) return;
    int cur = tgt[e];
    int lo  = (e == 0) ? 0 : tgt[e - 1] + 1;
    for (int n = lo; n <= cur; ++n) row_ptr[n] = e;
    if (e == N_EDGES - 1) {
        for (int n = cur + 1; n <= N_NODES; ++n) row_ptr[n] = N_EDGES;
    }
}

// ---------------------------------------------------------------------------
// Kernel 2: gather-sum, software-pipelined.
// One wave per node; 4 edge-groups x 16 lanes x float4.
// 8 edges in flight (2 stages), next-8 indices prefetched before the x-wait.
// ---------------------------------------------------------------------------
__global__ __launch_bounds__(256) void gather_sum(
    const float4* __restrict__ x4,        // [N_NODES, 16] float4
    const float*  __restrict__ ev,        // [N_EDGES]
    const int*    __restrict__ src,       // [N_EDGES]
    const int*    __restrict__ row_ptr,   // [N_NODES+1]
    float4*       __restrict__ out4)      // [N_NODES, 16] float4
{
    const int node = blockIdx.x * 4 + (threadIdx.x >> 6);
    if (node >= N_NODES) return;
    const int lane = threadIdx.x & 63;
    const int g    = lane >> 4;   // edge subgroup 0..3
    const int f    = lane & 15;   // float4 index within the row

    const int start = row_ptr[node];
    const int end   = row_ptr[node + 1];

    float4 acc = make_float4(0.f, 0.f, 0.f, 0.f);

    if (start < end) {
        // prologue: indices/weights for the first 8 edge slots
        int  ea = start + g, eb = start + 4 + g;
        bool va = ea < end,  vb = eb < end;
        int  esa = va ? ea : start, esb = vb ? eb : start;
        float wa = va ? ev[esa] : 0.0f;
        float wb = vb ? ev[esb] : 0.0f;
        int   sa = src[esa];
        int   sb = src[esb];

        for (int e0 = start; e0 < end; e0 += 8) {
            // issue both x gathers for the current 8 edges
            const float4 xa = x4[sa * 16 + f];
            const float4 xb = x4[sb * 16 + f];
            const float cwa = wa, cwb = wb;

            // prefetch indices/weights for the next 8 edges
            // (issued before the x-wait; clamped slots are harmless w=0 loads)
            {
                int  na = e0 + 8 + g, nb = e0 + 12 + g;
                bool vna = na < end,  vnb = nb < end;
                int  nsa = vna ? na : start, nsb = vnb ? nb : start;
                wa = vna ? ev[nsa] : 0.0f;
                wb = vnb ? ev[nsb] : 0.0f;
                sa = src[nsa];
                sb = src[nsb];
            }

            // FMA (first use of xa/xb -> the only long wait in steady state)
            acc.x = fmaf(cwa, xa.x, acc.x);
            acc.y = fmaf(cwa, xa.y, acc.y);
            acc.z = fmaf(cwa, xa.z, acc.z);
            acc.w = fmaf(cwa, xa.w, acc.w);
            acc.x = fmaf(cwb, xb.x, acc.x);
            acc.y = fmaf(cwb, xb.y, acc.y);
            acc.z = fmaf(cwb, xb.z, acc.z);
            acc.w = fmaf(cwb, xb.w, acc.w);
        }
    }

    // reduce the 4 edge-groups: lanes xor 16 then xor 32
    acc.x += __shfl_xor(acc.x, 16, 64);
    acc.y += __shfl_xor(acc.y, 16, 64);
    acc.z += __shfl_xor(acc.z, 16, 64);
    acc.w += __shfl_xor(acc.w, 16, 64);
    acc.x += __shfl_xor(acc.x, 32, 64);
    acc.y += __shfl_xor(acc.y, 32, 64);
    acc.z += __shfl_xor(acc.z, 32, 64);
    acc.w += __shfl_xor(acc.w, 32, 64);

    if (g == 0) out4[node * 16 + f] = acc;
}

extern "C" void kernel_launch(void* const* d_in, const int* in_sizes, int n_in,
                              void* d_out, int out_size, void* d_ws, size_t ws_size,
                              hipStream_t stream) {
    const float* x            = (const float*)d_in[0];
    const float* edge_values  = (const float*)d_in[1];
    const int*   target_index = (const int*)d_in[2];
    const int*   source_index = (const int*)d_in[3];
    float*       out          = (float*)d_out;
    int*         row_ptr      = (int*)d_ws;   // (N_NODES+1) * 4 bytes

    build_row_ptr<<<(N_EDGES + 255) / 256, 256, 0, stream>>>(target_index, row_ptr);

    gather_sum<<<(N_NODES + 3) / 4, 256, 0, stream>>>(
        (const float4*)x, edge_values, source_index, row_ptr, (float4*)out);
}